// Round 3
// baseline (244.612 us; speedup 1.0000x reference)
//
#include <hip/hip_runtime.h>
#include <math.h>

#define NPTS 50000
#define BATCH 2
#define CIN 64
#define C2 64
#define KNN 16
#define NCELL 125   // 5*5*5
#define MTOT 800000 // KNN*NPTS per (b,c)

// ws float layout:
// [0..6)    denom[b*3+c] = fp32(4*std)  (np-bit-exact)
// [8..14)   mean[b*3+c]  fp32
// [16..208) subtree sums: (b*3+c)*32 + s
// [4096..)  pass1: rel cache [bc][f] (4.8M floats); later reused as g[b][n][o]

// ---------- numpy-exact helpers ----------
__device__ __forceinline__ int to_cell32(float s) {
    // np: ((s + 1.0)*5 - 1.0)*0.5 ; round half-even ; clip 0..4
    float x = __fmul_rn(__fsub_rn(__fmul_rn(__fadd_rn(s, 1.0f), 5.0f), 1.0f), 0.5f);
    x = rintf(x);
    x = fminf(fmaxf(x, 0.0f), 4.0f);
    return (int)x;
}

// ---------------- Kernel PW: numpy-pairwise partial sums --------------------
// grid (32 subtrees, 6 bc), 256 threads = 256 leaves per 25000-subtree.
__global__ __launch_bounds__(256) void kpw(const float* __restrict__ xyz,
                                           const int* __restrict__ knn,
                                           float* __restrict__ wsf, int pass) {
    int s = blockIdx.x, bc = blockIdx.y;
    int b = bc / 3, c = bc % 3;
    const float* xb = xyz + (size_t)(b * 3 + c) * NPTS;
    const int* kb = knn + (size_t)b * NPTS * KNN;
    float* relc = wsf + 4096 + (size_t)bc * MTOT;
    int t = threadIdx.x;

    // walk 8 levels from (0, 25000): numpy split n2 = n/2 - (n/2)%8.
    // every node splits into equal leaf-counts -> leaf index = 8 bits.
    int off = 0, n = 25000;
    #pragma unroll
    for (int d = 7; d >= 0; --d) {
        int n2 = (n >> 1); n2 -= (n2 & 7);
        if ((t >> d) & 1) { off += n2; n -= n2; } else { n = n2; }
    }
    int base = s * 25000 + off;          // flat f in [0, 800000), f = kk*NPTS + nn
    float mean = wsf[8 + bc];            // valid in pass 2

    // numpy scalar leaf: r[0..7]=a[0..7]; r[j]+=a[i+j]; tree; (len%8==0, no tail)
    float r[8];
    #pragma unroll
    for (int j = 0; j < 8; ++j) {
        int f = base + j;
        float v;
        if (pass == 1) {
            int kk = f / NPTS, nn = f - kk * NPTS;
            int jj = kb[nn * KNN + kk];
            v = __fsub_rn(xb[jj], xb[nn]);
            relc[f] = v;
        } else {
            float d0 = __fsub_rn(relc[f], mean);
            v = __fmul_rn(d0, d0);
        }
        r[j] = v;
    }
    for (int i = 8; i < n; i += 8) {
        #pragma unroll
        for (int j = 0; j < 8; ++j) {
            int f = base + i + j;
            float v;
            if (pass == 1) {
                int kk = f / NPTS, nn = f - kk * NPTS;
                int jj = kb[nn * KNN + kk];
                v = __fsub_rn(xb[jj], xb[nn]);
                relc[f] = v;
            } else {
                float d0 = __fsub_rn(relc[f], mean);
                v = __fmul_rn(d0, d0);
            }
            r[j] = __fadd_rn(r[j], v);
        }
    }
    float res = __fadd_rn(__fadd_rn(__fadd_rn(r[0], r[1]), __fadd_rn(r[2], r[3])),
                          __fadd_rn(__fadd_rn(r[4], r[5]), __fadd_rn(r[6], r[7])));

    // exact pairwise halving over the 256 ordered leaf sums (perfect tree)
    __shared__ float lsum[256];
    lsum[t] = res; __syncthreads();
    for (int m = 128; m >= 1; m >>= 1) {
        float v = 0.0f;
        if (t < m) v = __fadd_rn(lsum[2 * t], lsum[2 * t + 1]);
        __syncthreads();
        if (t < m) lsum[t] = v;
        __syncthreads();
    }
    if (t == 0) wsf[16 + bc * 32 + s] = lsum[0];
}

// ---------------- Kernel FIN: top combine + finalize ------------------------
__global__ void kfin(float* __restrict__ wsf, int pass) {
    int bc = threadIdx.x;
    if (bc < 6) {
        float v[32];
        #pragma unroll
        for (int i = 0; i < 32; ++i) v[i] = wsf[16 + bc * 32 + i];
        #pragma unroll
        for (int m = 16; m >= 1; m >>= 1)
            #pragma unroll
            for (int i = 0; i < 16; ++i)
                if (i < m) v[i] = __fadd_rn(v[2 * i], v[2 * i + 1]);
        float S = v[0];
        if (pass == 1) {
            wsf[8 + bc] = S / 800000.0f;                 // np: sum/div fp32
        } else {
            float var = S / 799999.0f;                   // ddof=1
            wsf[bc] = __fmul_rn(4.0f, sqrtf(var));       // RADIUS*std (exact x4)
        }
    }
}

// ---------------- Kernel B: g[b][n][o] = sum_c W[o][c] * fea[b][c][n] --------
__global__ __launch_bounds__(256) void kgemm(const float* __restrict__ fea,
                                             const float* __restrict__ W,
                                             float* __restrict__ g) {
    int b = blockIdx.y;
    int n0 = blockIdx.x * 64;
    int nrem = NPTS - n0; if (nrem > 64) nrem = 64;
    __shared__ float flds[64][68];
    const float* fb = fea + (size_t)b * CIN * NPTS;
    int t = threadIdx.x;
    int j = t & 63, c0 = t >> 6;
    #pragma unroll
    for (int i = 0; i < 16; ++i) {
        int c = c0 + i * 4;
        flds[j][c] = (j < nrem) ? fb[(size_t)c * NPTS + n0 + j] : 0.0f;
    }
    int o = t & 63;
    float4 wr[16];
    #pragma unroll
    for (int i = 0; i < 16; ++i) wr[i] = ((const float4*)(W + o * CIN))[i];
    __syncthreads();
    int w = t >> 6;
    float* gb = g + ((size_t)b * NPTS + n0) * C2;
    #pragma unroll 1
    for (int p = w * 16; p < w * 16 + 16; ++p) {
        if (p >= nrem) break;
        float acc = 0.0f;
        #pragma unroll
        for (int i = 0; i < 16; ++i) {
            float4 f4 = *(const float4*)&flds[p][i * 4];
            acc += wr[i].x * f4.x + wr[i].y * f4.y + wr[i].z * f4.z + wr[i].w * f4.w;
        }
        gb[(size_t)p * C2 + o] = acc;
    }
}

// ---------------- Kernel C: fp32 np-exact cells + combine + coalesced write --
__global__ __launch_bounds__(256) void kmain(const float* __restrict__ xyz,
                                             const int* __restrict__ idx,
                                             const float* __restrict__ cb,
                                             const float* __restrict__ dw,
                                             const float* __restrict__ g,
                                             const float* __restrict__ wsf,
                                             float* __restrict__ out) {
    __shared__ float dwlds[C2 * NCELL];
    __shared__ int   idxlds[64 * KNN];
    __shared__ int   celllds[64 * KNN];
    __shared__ float ctr[3][64];
    __shared__ float res[128 * 65];
    int b = blockIdx.y;
    int n0 = blockIdx.x * 64;
    int t = threadIdx.x;
    int nrem = NPTS - n0; if (nrem > 64) nrem = 64;

    for (int i = t; i < C2 * NCELL; i += 256) dwlds[i] = dw[i];
    const int* ib = idx + ((size_t)b * NPTS + n0) * KNN;
    for (int i = t; i < nrem * KNN; i += 256) idxlds[i] = ib[i];
    const float* xb = xyz + (size_t)b * 3 * NPTS;
    if (t < 192) {
        int c = t >> 6, j = t & 63;
        if (j < nrem) ctr[c][j] = xb[c * NPTS + n0 + j];
    }
    __syncthreads();

    float dn0 = wsf[b * 3 + 0], dn1 = wsf[b * 3 + 1], dn2 = wsf[b * 3 + 2];
    for (int i = t; i < nrem * KNN; i += 256) {
        int p = i >> 4;
        int j = idxlds[i];
        float sx = __fsub_rn(xb[j],            ctr[0][p]) / dn0;
        float sy = __fsub_rn(xb[NPTS + j],     ctr[1][p]) / dn1;
        float sz = __fsub_rn(xb[2 * NPTS + j], ctr[2][p]) / dn2;
        celllds[i] = (to_cell32(sz) * 5 + to_cell32(sy)) * 5 + to_cell32(sx);
    }
    __syncthreads();

    int o = t & 63, wv = t >> 6;
    float cbo = cb[o];
    const float* gb = g + (size_t)b * NPTS * C2;
    for (int p = wv; p < nrem; p += 4) {
        int n = n0 + p;
        float gn = gb[(size_t)n * C2 + o];
        float k0 = dwlds[o * NCELL + celllds[p * 16]];
        float wsum = 0.0f, gsum = 0.0f, sk = 0.0f;
        #pragma unroll
        for (int k = 1; k < 16; ++k) {
            int j = idxlds[p * 16 + k];
            float gk = gb[(size_t)j * C2 + o];
            float kw = dwlds[o * NCELL + celllds[p * 16 + k]];
            wsum += kw * gk; gsum += gk; sk += kw;
        }
        res[o * 65 + p]        = cbo * (k0 + sk) + gn * (k0 - sk) + wsum;
        res[(64 + o) * 65 + p] = cbo + 0.0625f * (gsum - 14.0f * gn);
    }
    __syncthreads();

    float* ob = out + (size_t)b * 128 * NPTS;
    int j = t & 63;
    if (j < nrem) {
        for (int r = t >> 6; r < 128; r += 4)
            ob[(size_t)r * NPTS + n0 + j] = res[r * 65 + j];
    }
}

extern "C" void kernel_launch(void* const* d_in, const int* in_sizes, int n_in,
                              void* d_out, int out_size, void* d_ws, size_t ws_size,
                              hipStream_t stream) {
    const float* xyz   = (const float*)d_in[0];
    const float* fea   = (const float*)d_in[1];
    const int*   knn   = (const int*)d_in[2];
    const float* convw = (const float*)d_in[3];
    const float* convb = (const float*)d_in[4];
    const float* convdw= (const float*)d_in[5];
    float* out = (float*)d_out;
    float* wsf = (float*)d_ws;
    float* g   = wsf + 4096;   // overlaps rel cache; kgemm runs after kfin(2)

    int ntiles = (NPTS + 63) / 64;   // 782
    kpw  <<<dim3(32, 6), 256, 0, stream>>>(xyz, knn, wsf, 1);
    kfin <<<1, 64, 0, stream>>>(wsf, 1);
    kpw  <<<dim3(32, 6), 256, 0, stream>>>(xyz, knn, wsf, 2);
    kfin <<<1, 64, 0, stream>>>(wsf, 2);
    kgemm<<<dim3(ntiles, BATCH), 256, 0, stream>>>(fea, convw, g);
    kmain<<<dim3(ntiles, BATCH), 256, 0, stream>>>(xyz, knn, convb, convdw, g, wsf, out);
}

// Round 4
// 186.017 us; speedup vs baseline: 1.3150x; 1.3150x over previous
//
#include <hip/hip_runtime.h>
#include <hip/hip_bf16.h>
#include <math.h>

#define NPTS 50000
#define BATCH 2
#define CIN 64
#define C2 64
#define KNN 16
#define NCELL 125   // 5*5*5
#define MTOT 800000 // KNN*NPTS per (b,c)

// ws float layout:
// [0..6)      denom[b*3+c] = fp32(4*std)  (np-bit-exact)
// [8..14)     mean[b*3+c]
// [16..1552)  block partials: (bc*32+s)*8+blk
// [4096..)    g[b][n][o] as bf16 : BATCH*NPTS*C2 (12.8 MB)

__device__ __forceinline__ int to_cell32(float s) {
    float x = __fmul_rn(__fsub_rn(__fmul_rn(__fadd_rn(s, 1.0f), 5.0f), 1.0f), 0.5f);
    x = rintf(x);                       // half-to-even, matches np.round
    x = fminf(fmaxf(x, 0.0f), 4.0f);
    return (int)x;
}

// ---------------- Kernel PW: numpy-pairwise partial sums, lane-per-chain ----
// grid (32 subtrees * 8 blocks, 6 bc); block 256 = 32 leaves * 8 chains.
__global__ __launch_bounds__(256) void kpw(const float* __restrict__ xyz,
                                           const int* __restrict__ knn,
                                           float* __restrict__ wsf, int pass) {
    int bx = blockIdx.x;
    int s = bx >> 3, blk = bx & 7;
    int bc = blockIdx.y;
    int b = bc / 3, c = bc % 3;
    const float* xb = xyz + (size_t)(b * 3 + c) * NPTS;
    const int* kb = knn + (size_t)b * NPTS * KNN;
    int t = threadIdx.x;
    int l = blk * 32 + (t >> 3);       // leaf index 0..255 within subtree
    int j = t & 7;                     // numpy accumulator chain

    // bit-walk the numpy split (n2 = n/2 - n/2%8) down 8 levels from n=25000
    int off = 0, n = 25000;
    #pragma unroll
    for (int d = 7; d >= 0; --d) {
        int n2 = (n >> 1); n2 -= (n2 & 7);
        if ((l >> d) & 1) { off += n2; n -= n2; } else { n = n2; }
    }
    int base = s * 25000 + off;        // flat f = kk*NPTS + nn
    float mean = wsf[8 + bc];          // valid only in pass 2

    // chain j: elements base+j, base+j+8, ... (numpy r[j] sequence)
    float r;
    {
        int f = base + j;
        int kk = f / NPTS, nn = f - kk * NPTS;
        int jj = kb[nn * KNN + kk];
        float v = __fsub_rn(xb[jj], xb[nn]);
        if (pass == 2) { float d0 = __fsub_rn(v, mean); v = __fmul_rn(d0, d0); }
        r = v;
    }
    for (int i = j + 8; i < n; i += 8) {
        int f = base + i;
        int kk = f / NPTS, nn = f - kk * NPTS;
        int jj = kb[nn * KNN + kk];
        float v = __fsub_rn(xb[jj], xb[nn]);
        if (pass == 2) { float d0 = __fsub_rn(v, mean); v = __fmul_rn(d0, d0); }
        r = __fadd_rn(r, v);
    }

    // exact numpy 8-acc combine: fp add is commutative -> xor tree matches bits
    float r1 = __fadd_rn(r,  __shfl_xor(r, 1));
    float r2 = __fadd_rn(r1, __shfl_xor(r1, 2));
    float r3 = __fadd_rn(r2, __shfl_xor(r2, 4));

    __shared__ float lsum[32];
    if (j == 0) lsum[t >> 3] = r3;
    __syncthreads();
    // bottom 5 levels of the 256-leaf pairwise tree (this block = aligned 32 leaves)
    for (int m = 16; m >= 1; m >>= 1) {
        float v = 0.0f;
        if (t < m) v = __fadd_rn(lsum[2 * t], lsum[2 * t + 1]);
        __syncthreads();
        if (t < m) lsum[t] = v;
        __syncthreads();
    }
    if (t == 0) wsf[16 + ((size_t)bc * 32 + s) * 8 + blk] = lsum[0];
}

// ---------------- Kernel FIN: finish tree + finalize ------------------------
__global__ void kfin(float* __restrict__ wsf, int pass) {
    int bc = threadIdx.x;
    if (bc < 6) {
        float v[32];
        for (int s2 = 0; s2 < 32; ++s2) {
            const float* p = wsf + 16 + ((size_t)bc * 32 + s2) * 8;
            float a  = __fadd_rn(__fadd_rn(p[0], p[1]), __fadd_rn(p[2], p[3]));
            float b2 = __fadd_rn(__fadd_rn(p[4], p[5]), __fadd_rn(p[6], p[7]));
            v[s2] = __fadd_rn(a, b2);
        }
        for (int m = 16; m >= 1; m >>= 1)
            for (int i = 0; i < m; ++i) v[i] = __fadd_rn(v[2 * i], v[2 * i + 1]);
        float S = v[0];
        if (pass == 1) {
            wsf[8 + bc] = S / 800000.0f;
        } else {
            float var = S / 799999.0f;                  // ddof=1
            wsf[bc] = __fmul_rn(4.0f, sqrtf(var));      // RADIUS*std
        }
    }
}

// ---------------- Kernel B: g[b][n][o] = sum_c W[o][c]*fea[b][c][n] -> bf16 --
__global__ __launch_bounds__(256) void kgemm(const float* __restrict__ fea,
                                             const float* __restrict__ W,
                                             __hip_bfloat16* __restrict__ g) {
    int b = blockIdx.y;
    int n0 = blockIdx.x * 64;
    int nrem = NPTS - n0; if (nrem > 64) nrem = 64;
    __shared__ float flds[64][68];
    const float* fb = fea + (size_t)b * CIN * NPTS;
    int t = threadIdx.x;
    int j = t & 63, c0 = t >> 6;
    #pragma unroll
    for (int i = 0; i < 16; ++i) {
        int c = c0 + i * 4;
        flds[j][c] = (j < nrem) ? fb[(size_t)c * NPTS + n0 + j] : 0.0f;
    }
    int o = t & 63;
    float4 wr[16];
    #pragma unroll
    for (int i = 0; i < 16; ++i) wr[i] = ((const float4*)(W + o * CIN))[i];
    __syncthreads();
    int w = t >> 6;
    __hip_bfloat16* gb = g + ((size_t)b * NPTS + n0) * C2;
    #pragma unroll 1
    for (int p = w * 16; p < w * 16 + 16; ++p) {
        if (p >= nrem) break;
        float acc = 0.0f;
        #pragma unroll
        for (int i = 0; i < 16; ++i) {
            float4 f4 = *(const float4*)&flds[p][i * 4];
            acc += wr[i].x * f4.x + wr[i].y * f4.y + wr[i].z * f4.z + wr[i].w * f4.w;
        }
        gb[(size_t)p * C2 + o] = __float2bfloat16(acc);   // coalesced 128B
    }
}

// ---------------- Kernel C: cells + bf16 gathers + coalesced write ----------
__global__ __launch_bounds__(256) void kmain(const float* __restrict__ xyz,
                                             const int* __restrict__ idx,
                                             const float* __restrict__ cb,
                                             const float* __restrict__ dw,
                                             const __hip_bfloat16* __restrict__ g,
                                             const float* __restrict__ wsf,
                                             float* __restrict__ out) {
    __shared__ __hip_bfloat16 dwlds[C2 * NCELL];   // 16000 B
    __shared__ unsigned char  celllds[64 * KNN];   // 1024 B
    __shared__ float          ctr[3][64];          // 768 B
    __shared__ float          res[128 * 65];       // 33280 B  -> total ~51 KB
    int b = blockIdx.y;
    int n0 = blockIdx.x * 64;
    int t = threadIdx.x;
    int nrem = NPTS - n0; if (nrem > 64) nrem = 64;

    for (int i = t; i < C2 * NCELL; i += 256) dwlds[i] = __float2bfloat16(dw[i]);
    const float* xb = xyz + (size_t)b * 3 * NPTS;
    if (t < 192) {
        int c = t >> 6, j = t & 63;
        if (j < nrem) ctr[c][j] = xb[c * NPTS + n0 + j];
    }
    const int* ib = idx + ((size_t)b * NPTS + n0) * KNN;
    __syncthreads();

    float dn0 = wsf[b * 3 + 0], dn1 = wsf[b * 3 + 1], dn2 = wsf[b * 3 + 2];
    for (int i = t; i < nrem * KNN; i += 256) {
        int p = i >> 4;
        int j = ib[i];
        float sx = __fsub_rn(xb[j],            ctr[0][p]) / dn0;
        float sy = __fsub_rn(xb[NPTS + j],     ctr[1][p]) / dn1;
        float sz = __fsub_rn(xb[2 * NPTS + j], ctr[2][p]) / dn2;
        celllds[i] = (unsigned char)((to_cell32(sz) * 5 + to_cell32(sy)) * 5 + to_cell32(sx));
    }
    __syncthreads();

    int o = t & 63, wv = t >> 6;
    float cbo = cb[o];
    const __hip_bfloat16* gb = g + (size_t)b * NPTS * C2;
    for (int p = wv; p < nrem; p += 4) {
        int n = n0 + p;
        float gn = __bfloat162float(gb[(size_t)n * C2 + o]);
        float k0 = __bfloat162float(dwlds[o * NCELL + celllds[p * 16]]);
        const int* row = ib + p * 16;
        float wsum = 0.0f, gsum = 0.0f, sk = 0.0f;
        #pragma unroll
        for (int k = 1; k < 16; ++k) {
            int jj = row[k];                                   // uniform broadcast
            float gk = __bfloat162float(gb[(size_t)jj * C2 + o]);  // 128B gather
            float kw = __bfloat162float(dwlds[o * NCELL + celllds[p * 16 + k]]);
            wsum += kw * gk; gsum += gk; sk += kw;
        }
        res[o * 65 + p]        = cbo * (k0 + sk) + gn * (k0 - sk) + wsum;
        res[(64 + o) * 65 + p] = cbo + 0.0625f * (gsum - 14.0f * gn);
    }
    __syncthreads();

    float* ob = out + (size_t)b * 128 * NPTS;
    int j = t & 63;
    if (j < nrem) {
        for (int r = t >> 6; r < 128; r += 4)
            ob[(size_t)r * NPTS + n0 + j] = res[r * 65 + j];   // coalesced rows
    }
}

extern "C" void kernel_launch(void* const* d_in, const int* in_sizes, int n_in,
                              void* d_out, int out_size, void* d_ws, size_t ws_size,
                              hipStream_t stream) {
    const float* xyz   = (const float*)d_in[0];
    const float* fea   = (const float*)d_in[1];
    const int*   knn   = (const int*)d_in[2];
    const float* convw = (const float*)d_in[3];
    const float* convb = (const float*)d_in[4];
    const float* convdw= (const float*)d_in[5];
    float* out = (float*)d_out;
    float* wsf = (float*)d_ws;
    __hip_bfloat16* g = (__hip_bfloat16*)(wsf + 4096);

    int ntiles = (NPTS + 63) / 64;   // 782
    kgemm<<<dim3(ntiles, BATCH), 256, 0, stream>>>(fea, convw, g);
    kpw  <<<dim3(256, 6), 256, 0, stream>>>(xyz, knn, wsf, 1);
    kfin <<<1, 64, 0, stream>>>(wsf, 1);
    kpw  <<<dim3(256, 6), 256, 0, stream>>>(xyz, knn, wsf, 2);
    kfin <<<1, 64, 0, stream>>>(wsf, 2);
    kmain<<<dim3(ntiles, BATCH), 256, 0, stream>>>(xyz, knn, convb, convdw, g, wsf, out);
}

// Round 5
// 174.676 us; speedup vs baseline: 1.4004x; 1.0649x over previous
//
#include <hip/hip_runtime.h>
#include <hip/hip_bf16.h>
#include <math.h>

#define NPTS 50000
#define BATCH 2
#define CIN 64
#define C2 64
#define KNN 16
#define NCELL 125
#define MTOT 800000

// ws float layout:
// [0..6)      denom[b*3+c] = fp32(4*std)  (np-bit-exact)
// [8..14)     mean[b*3+c]
// [16..1552)  block partials: (bc*32+s)*8+blk
// [4096..)    pass1/2: relc[bc][MTOT] fp32 (19.2MB); after kfin2 reused as
//             g[b][n][o] bf16 (12.8MB)

__device__ __forceinline__ float bflo(unsigned int v) { return __uint_as_float(v << 16); }
__device__ __forceinline__ float bfhi(unsigned int v) { return __uint_as_float(v & 0xffff0000u); }
__device__ __forceinline__ float bfs(unsigned short v) { return __uint_as_float((unsigned int)v << 16); }

__device__ __forceinline__ int to_cell32(float s) {
    float x = __fmul_rn(__fsub_rn(__fmul_rn(__fadd_rn(s, 1.0f), 5.0f), 1.0f), 0.5f);
    x = rintf(x);                       // half-to-even, matches np.round
    x = fminf(fmaxf(x, 0.0f), 4.0f);
    return (int)x;
}

// ---------------- Kernel PW: numpy-pairwise partial sums, c-merged ----------
// grid (32 subtrees * 8 blocks, 2 b); block 256 = 32 leaves * 8 chains.
__global__ __launch_bounds__(256) void kpw(const float* __restrict__ xyz,
                                           const int* __restrict__ knn,
                                           float* __restrict__ wsf, int pass) {
    int bx = blockIdx.x;
    int s = bx >> 3, blk = bx & 7;
    int b = blockIdx.y;
    const float* xb = xyz + (size_t)b * 3 * NPTS;
    const int* kb = knn + (size_t)b * NPTS * KNN;
    float* relc = wsf + 4096 + (size_t)b * 3 * MTOT;
    int t = threadIdx.x;
    int l = blk * 32 + (t >> 3);       // leaf 0..255 within subtree
    int j = t & 7;                     // numpy accumulator chain

    // bit-walk numpy split (n2 = n/2 - n/2%8) down 8 levels from n=25000
    int off = 0, n = 25000;
    #pragma unroll
    for (int d = 7; d >= 0; --d) {
        int n2 = (n >> 1); n2 -= (n2 & 7);
        if ((l >> d) & 1) { off += n2; n -= n2; } else { n = n2; }
    }
    int base = s * 25000 + off;        // flat f = kk*NPTS + nn
    float m0 = wsf[8 + b * 3 + 0], m1 = wsf[8 + b * 3 + 1], m2 = wsf[8 + b * 3 + 2];

    float r0 = 0.0f, r1 = 0.0f, r2 = 0.0f;   // 0+v == v exactly (v never -0)
    for (int i = j; i < n; i += 8) {
        int f = base + i;
        float v0, v1, v2;
        if (pass == 1) {
            int kk = f / NPTS, nn = f - kk * NPTS;
            int jj = kb[nn * KNN + kk];
            v0 = __fsub_rn(xb[jj],            xb[nn]);
            v1 = __fsub_rn(xb[NPTS + jj],     xb[NPTS + nn]);
            v2 = __fsub_rn(xb[2 * NPTS + jj], xb[2 * NPTS + nn]);
            relc[f] = v0; relc[MTOT + f] = v1; relc[2 * MTOT + f] = v2;
        } else {
            v0 = relc[f]; v1 = relc[MTOT + f]; v2 = relc[2 * MTOT + f];
            float d0 = __fsub_rn(v0, m0); v0 = __fmul_rn(d0, d0);
            float d1 = __fsub_rn(v1, m1); v1 = __fmul_rn(d1, d1);
            float d2 = __fsub_rn(v2, m2); v2 = __fmul_rn(d2, d2);
        }
        r0 = __fadd_rn(r0, v0); r1 = __fadd_rn(r1, v1); r2 = __fadd_rn(r2, v2);
    }

    // numpy 8-acc combine (fp add commutative -> xor tree matches bits)
    float a0 = __fadd_rn(r0, __shfl_xor(r0, 1));
    a0 = __fadd_rn(a0, __shfl_xor(a0, 2));
    a0 = __fadd_rn(a0, __shfl_xor(a0, 4));
    float a1 = __fadd_rn(r1, __shfl_xor(r1, 1));
    a1 = __fadd_rn(a1, __shfl_xor(a1, 2));
    a1 = __fadd_rn(a1, __shfl_xor(a1, 4));
    float a2 = __fadd_rn(r2, __shfl_xor(r2, 1));
    a2 = __fadd_rn(a2, __shfl_xor(a2, 2));
    a2 = __fadd_rn(a2, __shfl_xor(a2, 4));

    __shared__ float lsum[32];
    #pragma unroll
    for (int c = 0; c < 3; ++c) {
        float rc = (c == 0) ? a0 : ((c == 1) ? a1 : a2);
        __syncthreads();
        if (j == 0) lsum[t >> 3] = rc;
        __syncthreads();
        for (int m = 16; m >= 1; m >>= 1) {
            float v = 0.0f;
            if (t < m) v = __fadd_rn(lsum[2 * t], lsum[2 * t + 1]);
            __syncthreads();
            if (t < m) lsum[t] = v;
            __syncthreads();
        }
        if (t == 0) wsf[16 + ((size_t)(b * 3 + c) * 32 + s) * 8 + blk] = lsum[0];
    }
}

// ---------------- Kernel FIN: finish tree + finalize ------------------------
__global__ void kfin(float* __restrict__ wsf, int pass) {
    int bc = threadIdx.x;
    if (bc < 6) {
        float v[32];
        #pragma unroll
        for (int s2 = 0; s2 < 32; ++s2) {
            const float* p = wsf + 16 + ((size_t)bc * 32 + s2) * 8;
            float a  = __fadd_rn(__fadd_rn(p[0], p[1]), __fadd_rn(p[2], p[3]));
            float b2 = __fadd_rn(__fadd_rn(p[4], p[5]), __fadd_rn(p[6], p[7]));
            v[s2] = __fadd_rn(a, b2);
        }
        #pragma unroll
        for (int m = 16; m >= 1; m >>= 1)
            #pragma unroll
            for (int i = 0; i < 16; ++i)
                if (i < m) v[i] = __fadd_rn(v[2 * i], v[2 * i + 1]);
        float S = v[0];
        if (pass == 1) {
            wsf[8 + bc] = S / 800000.0f;
        } else {
            float var = S / 799999.0f;                  // ddof=1
            wsf[bc] = __fmul_rn(4.0f, sqrtf(var));      // RADIUS*std
        }
    }
}

// ---------------- Kernel B: g = W*fea -> bf16, 4 accumulators ---------------
__global__ __launch_bounds__(256) void kgemm(const float* __restrict__ fea,
                                             const float* __restrict__ W,
                                             unsigned short* __restrict__ g) {
    int b = blockIdx.y;
    int n0 = blockIdx.x * 64;
    int nrem = NPTS - n0; if (nrem > 64) nrem = 64;
    __shared__ float flds[64][68];
    const float* fb = fea + (size_t)b * CIN * NPTS;
    int t = threadIdx.x;
    int j = t & 63, c0 = t >> 6;
    #pragma unroll
    for (int i = 0; i < 16; ++i) {
        int c = c0 + i * 4;
        flds[j][c] = (j < nrem) ? fb[(size_t)c * NPTS + n0 + j] : 0.0f;
    }
    int o = t & 63;
    float4 wr[16];
    #pragma unroll
    for (int i = 0; i < 16; ++i) wr[i] = ((const float4*)(W + o * CIN))[i];
    __syncthreads();
    int w = t >> 6;
    unsigned short* gb = g + ((size_t)b * NPTS + n0) * C2;
    #pragma unroll 1
    for (int p = w * 16; p < w * 16 + 16; ++p) {
        if (p >= nrem) break;
        float acc0 = 0, acc1 = 0, acc2 = 0, acc3 = 0;
        #pragma unroll
        for (int i = 0; i < 16; i += 4) {
            float4 f0 = *(const float4*)&flds[p][(i + 0) * 4];
            float4 f1 = *(const float4*)&flds[p][(i + 1) * 4];
            float4 f2 = *(const float4*)&flds[p][(i + 2) * 4];
            float4 f3 = *(const float4*)&flds[p][(i + 3) * 4];
            acc0 += wr[i+0].x*f0.x + wr[i+0].y*f0.y + wr[i+0].z*f0.z + wr[i+0].w*f0.w;
            acc1 += wr[i+1].x*f1.x + wr[i+1].y*f1.y + wr[i+1].z*f1.z + wr[i+1].w*f1.w;
            acc2 += wr[i+2].x*f2.x + wr[i+2].y*f2.y + wr[i+2].z*f2.z + wr[i+2].w*f2.w;
            acc3 += wr[i+3].x*f3.x + wr[i+3].y*f3.y + wr[i+3].z*f3.z + wr[i+3].w*f3.w;
        }
        float acc = (acc0 + acc1) + (acc2 + acc3);
        __hip_bfloat16 hb = __float2bfloat16(acc);
        gb[(size_t)p * C2 + o] = *(unsigned short*)&hb;   // coalesced 128B
    }
}

// ---------------- Kernel C: h-split ushort2 gathers + 2-phase res -----------
__global__ __launch_bounds__(256, 4) void kmain(const float* __restrict__ xyz,
                                                const int* __restrict__ idx,
                                                const float* __restrict__ cb,
                                                const float* __restrict__ dw,
                                                const unsigned short* __restrict__ g,
                                                const float* __restrict__ wsf,
                                                float* __restrict__ out) {
    __shared__ unsigned short dwlds[C2 * 130];     // stride 130 -> 2-way banks
    __shared__ unsigned char  celllds[64 * KNN];
    __shared__ float          ctr[3][64];
    __shared__ float          resw[64 * 65];       // single half, 16.6KB
    int b = blockIdx.y;
    int n0 = blockIdx.x * 64;
    int t = threadIdx.x;
    int nrem = NPTS - n0; if (nrem > 64) nrem = 64;

    for (int i = t; i < C2 * NCELL; i += 256) {
        int oo = i / NCELL, cc = i - oo * NCELL;
        __hip_bfloat16 hb = __float2bfloat16(dw[i]);
        dwlds[oo * 130 + cc] = *(unsigned short*)&hb;
    }
    const float* xb = xyz + (size_t)b * 3 * NPTS;
    if (t < 192) {
        int c = t >> 6, jx = t & 63;
        if (jx < nrem) ctr[c][jx] = xb[c * NPTS + n0 + jx];
    }
    const int* ib = idx + ((size_t)b * NPTS + n0) * KNN;
    __syncthreads();

    float dn0 = wsf[b * 3 + 0], dn1 = wsf[b * 3 + 1], dn2 = wsf[b * 3 + 2];
    for (int i = t; i < nrem * KNN; i += 256) {
        int p = i >> 4;
        int jx = ib[i];
        float sx = __fsub_rn(xb[jx],            ctr[0][p]) / dn0;
        float sy = __fsub_rn(xb[NPTS + jx],     ctr[1][p]) / dn1;
        float sz = __fsub_rn(xb[2 * NPTS + jx], ctr[2][p]) / dn2;
        celllds[i] = (unsigned char)((to_cell32(sz) * 5 + to_cell32(sy)) * 5 + to_cell32(sx));
    }
    __syncthreads();

    int w = t >> 6, lane = t & 63, h = lane >> 5, u = lane & 31;
    int o0 = 2 * u, o1 = 2 * u + 1;
    float cb0 = cb[o0], cb1 = cb[o1];
    float st0[16], st1[16];
    const unsigned short* gbp = g + (size_t)b * NPTS * C2;

    #pragma unroll
    for (int i = 0; i < 16; ++i) {
        int p = w + i * 4;
        if (p < nrem) {
            const int* row = ib + p * KNN;
            int nidx = n0 + p;
            unsigned int gnv = *(const unsigned int*)(gbp + (size_t)nidx * C2 + 2 * u);
            float gn0 = bflo(gnv), gn1 = bfhi(gnv);
            int cell0 = celllds[p * KNN];
            float k00 = bfs(dwlds[o0 * 130 + cell0]);
            float k01 = bfs(dwlds[o1 * 130 + cell0]);
            float ws0 = 0, ws1 = 0, gs0 = 0, gs1 = 0, sk0 = 0, sk1 = 0;
            #pragma unroll
            for (int m = 0; m < 7; ++m) {
                int k = 1 + h + 2 * m;                 // h=0: odd 1..13, h=1: even 2..14
                int jj = row[k];
                int cell = celllds[p * KNN + k];
                unsigned int gv = *(const unsigned int*)(gbp + (size_t)jj * C2 + 2 * u);
                float g0 = bflo(gv), g1 = bfhi(gv);
                float kw0 = bfs(dwlds[o0 * 130 + cell]);
                float kw1 = bfs(dwlds[o1 * 130 + cell]);
                ws0 = fmaf(kw0, g0, ws0); ws1 = fmaf(kw1, g1, ws1);
                gs0 += g0; gs1 += g1; sk0 += kw0; sk1 += kw1;
            }
            if (h == 0) {                              // k = 15
                int jj = row[15];
                int cell = celllds[p * KNN + 15];
                unsigned int gv = *(const unsigned int*)(gbp + (size_t)jj * C2 + 2 * u);
                float g0 = bflo(gv), g1 = bfhi(gv);
                float kw0 = bfs(dwlds[o0 * 130 + cell]);
                float kw1 = bfs(dwlds[o1 * 130 + cell]);
                ws0 = fmaf(kw0, g0, ws0); ws1 = fmaf(kw1, g1, ws1);
                gs0 += g0; gs1 += g1; sk0 += kw0; sk1 += kw1;
            }
            ws0 += __shfl_xor(ws0, 32); ws1 += __shfl_xor(ws1, 32);
            gs0 += __shfl_xor(gs0, 32); gs1 += __shfl_xor(gs1, 32);
            sk0 += __shfl_xor(sk0, 32); sk1 += __shfl_xor(sk1, 32);
            if (h == 0) {
                resw[o0 * 65 + p] = cb0 * (k00 + sk0) + gn0 * (k00 - sk0) + ws0;
                resw[o1 * 65 + p] = cb1 * (k01 + sk1) + gn1 * (k01 - sk1) + ws1;
            }
            st0[i] = cb0 + 0.0625f * (gs0 - 14.0f * gn0);
            st1[i] = cb1 + 0.0625f * (gs1 - 14.0f * gn1);
        }
    }
    __syncthreads();

    float* ob = out + (size_t)b * 128 * NPTS;
    int jn = t & 63;
    if (jn < nrem)
        for (int r = t >> 6; r < 64; r += 4)
            ob[(size_t)r * NPTS + n0 + jn] = resw[r * 65 + jn];
    __syncthreads();
    if (h == 0) {
        #pragma unroll
        for (int i = 0; i < 16; ++i) {
            int p = w + i * 4;
            if (p < nrem) { resw[o0 * 65 + p] = st0[i]; resw[o1 * 65 + p] = st1[i]; }
        }
    }
    __syncthreads();
    if (jn < nrem)
        for (int r = t >> 6; r < 64; r += 4)
            ob[(size_t)(64 + r) * NPTS + n0 + jn] = resw[r * 65 + jn];
}

extern "C" void kernel_launch(void* const* d_in, const int* in_sizes, int n_in,
                              void* d_out, int out_size, void* d_ws, size_t ws_size,
                              hipStream_t stream) {
    const float* xyz   = (const float*)d_in[0];
    const float* fea   = (const float*)d_in[1];
    const int*   knn   = (const int*)d_in[2];
    const float* convw = (const float*)d_in[3];
    const float* convb = (const float*)d_in[4];
    const float* convdw= (const float*)d_in[5];
    float* out = (float*)d_out;
    float* wsf = (float*)d_ws;
    unsigned short* g = (unsigned short*)(wsf + 4096);

    int ntiles = (NPTS + 63) / 64;   // 782
    kpw  <<<dim3(256, BATCH), 256, 0, stream>>>(xyz, knn, wsf, 1);
    kfin <<<1, 64, 0, stream>>>(wsf, 1);
    kpw  <<<dim3(256, BATCH), 256, 0, stream>>>(xyz, knn, wsf, 2);
    kfin <<<1, 64, 0, stream>>>(wsf, 2);
    kgemm<<<dim3(ntiles, BATCH), 256, 0, stream>>>(fea, convw, g);
    kmain<<<dim3(ntiles, BATCH), 256, 0, stream>>>(xyz, knn, convb, convdw, g, wsf, out);
}

// Round 6
// 151.411 us; speedup vs baseline: 1.6155x; 1.1537x over previous
//
#include <hip/hip_runtime.h>
#include <hip/hip_bf16.h>
#include <math.h>

#define NPTS 50000
#define BATCH 2
#define CIN 64
#define C2 64
#define KNN 16
#define NCELL 125
#define MTOT 800000

// wsf layout (floats):
// [16..1552)   PART1: pass-1 partials  (b*3+c)*256 + s*8 + blk
// [2048..3584) PART2: pass-2 partials  same indexing
// [4096..)     g[b][n][o] bf16 (12.8 MB)
// rel cache (19.2 MB) lives in d_out (fully overwritten by kmain afterwards).

__device__ __forceinline__ float bflo(unsigned int v) { return __uint_as_float(v << 16); }
__device__ __forceinline__ float bfhi(unsigned int v) { return __uint_as_float(v & 0xffff0000u); }

__device__ __forceinline__ int to_cell32(float s) {
    float x = __fmul_rn(__fsub_rn(__fmul_rn(__fadd_rn(s, 1.0f), 5.0f), 1.0f), 0.5f);
    x = rintf(x);                       // half-to-even, matches np.round
    x = fminf(fmaxf(x, 0.0f), 4.0f);
    return (int)x;
}

// exact kfin combine: 32 groups of 8 -> scalar (numpy pairwise order)
__device__ __forceinline__ float reduce256(const float* __restrict__ p) {
    float v[32];
    #pragma unroll
    for (int s2 = 0; s2 < 32; ++s2) {
        const float* q = p + s2 * 8;
        float a  = __fadd_rn(__fadd_rn(q[0], q[1]), __fadd_rn(q[2], q[3]));
        float b2 = __fadd_rn(__fadd_rn(q[4], q[5]), __fadd_rn(q[6], q[7]));
        v[s2] = __fadd_rn(a, b2);
    }
    #pragma unroll
    for (int m = 16; m >= 1; m >>= 1)
        #pragma unroll
        for (int i = 0; i < 16; ++i)
            if (i < m) v[i] = __fadd_rn(v[2 * i], v[2 * i + 1]);
    return v[0];
}

// ---------------- L1: fused GEMM (blocks 0..1563) + PW pass 1 (1564..2075) --
__global__ __launch_bounds__(256) void kfuse1(const float* __restrict__ xyz,
                                              const int* __restrict__ knn,
                                              const float* __restrict__ fea,
                                              const float* __restrict__ W,
                                              unsigned short* __restrict__ g,
                                              float* __restrict__ relc0,
                                              float* __restrict__ wsf) {
    __shared__ float sh[64 * 68];
    int bx = blockIdx.x;
    int t = threadIdx.x;
    if (bx < 1564) {
        // ---- GEMM role: g[b][n][o] = sum_c W[o][c]*fea[b][c][n] -> bf16 ----
        int b = (bx >= 782);
        int tile = bx - b * 782;
        int n0 = tile * 64;
        int nrem = NPTS - n0; if (nrem > 64) nrem = 64;
        float (*flds)[68] = (float (*)[68])sh;
        const float* fb = fea + (size_t)b * CIN * NPTS;
        int j = t & 63, c0 = t >> 6;
        #pragma unroll
        for (int i = 0; i < 16; ++i) {
            int c = c0 + i * 4;
            flds[j][c] = (j < nrem) ? fb[(size_t)c * NPTS + n0 + j] : 0.0f;
        }
        int o = t & 63;
        float4 wr[16];
        #pragma unroll
        for (int i = 0; i < 16; ++i) wr[i] = ((const float4*)(W + o * CIN))[i];
        __syncthreads();
        int w = t >> 6;
        unsigned short* gb = g + ((size_t)b * NPTS + n0) * C2;
        #pragma unroll 1
        for (int p = w * 16; p < w * 16 + 16; ++p) {
            if (p >= nrem) break;
            float acc0 = 0, acc1 = 0, acc2 = 0, acc3 = 0;
            #pragma unroll
            for (int i = 0; i < 16; i += 4) {
                float4 f0 = *(const float4*)&flds[p][(i + 0) * 4];
                float4 f1 = *(const float4*)&flds[p][(i + 1) * 4];
                float4 f2 = *(const float4*)&flds[p][(i + 2) * 4];
                float4 f3 = *(const float4*)&flds[p][(i + 3) * 4];
                acc0 += wr[i+0].x*f0.x + wr[i+0].y*f0.y + wr[i+0].z*f0.z + wr[i+0].w*f0.w;
                acc1 += wr[i+1].x*f1.x + wr[i+1].y*f1.y + wr[i+1].z*f1.z + wr[i+1].w*f1.w;
                acc2 += wr[i+2].x*f2.x + wr[i+2].y*f2.y + wr[i+2].z*f2.z + wr[i+2].w*f2.w;
                acc3 += wr[i+3].x*f3.x + wr[i+3].y*f3.y + wr[i+3].z*f3.z + wr[i+3].w*f3.w;
            }
            float acc = (acc0 + acc1) + (acc2 + acc3);
            __hip_bfloat16 hb = __float2bfloat16(acc);
            gb[(size_t)p * C2 + o] = *(unsigned short*)&hb;
        }
    } else {
        // ---- PW pass 1: rel materialization + numpy-pairwise partial sums --
        int idx = bx - 1564;              // 0..511
        int b = idx >> 8;
        int r = idx & 255;
        int s = r >> 3, blk = r & 7;
        const float* xb = xyz + (size_t)b * 3 * NPTS;
        const int* kb = knn + (size_t)b * NPTS * KNN;
        float* relc = relc0 + (size_t)b * 3 * MTOT;
        int l = blk * 32 + (t >> 3);
        int j = t & 7;
        int off = 0, n = 25000;
        #pragma unroll
        for (int d = 7; d >= 0; --d) {
            int n2 = (n >> 1); n2 -= (n2 & 7);
            if ((l >> d) & 1) { off += n2; n -= n2; } else { n = n2; }
        }
        int base = s * 25000 + off;
        float r0 = 0.0f, r1 = 0.0f, r2 = 0.0f;
        for (int i = j; i < n; i += 8) {
            int f = base + i;
            int kk = f / NPTS, nn = f - kk * NPTS;
            int jj = kb[nn * KNN + kk];
            float v0 = __fsub_rn(xb[jj],            xb[nn]);
            float v1 = __fsub_rn(xb[NPTS + jj],     xb[NPTS + nn]);
            float v2 = __fsub_rn(xb[2 * NPTS + jj], xb[2 * NPTS + nn]);
            relc[f] = v0; relc[MTOT + f] = v1; relc[2 * MTOT + f] = v2;
            r0 = __fadd_rn(r0, v0); r1 = __fadd_rn(r1, v1); r2 = __fadd_rn(r2, v2);
        }
        float a0 = __fadd_rn(r0, __shfl_xor(r0, 1));
        a0 = __fadd_rn(a0, __shfl_xor(a0, 2));
        a0 = __fadd_rn(a0, __shfl_xor(a0, 4));
        float a1 = __fadd_rn(r1, __shfl_xor(r1, 1));
        a1 = __fadd_rn(a1, __shfl_xor(a1, 2));
        a1 = __fadd_rn(a1, __shfl_xor(a1, 4));
        float a2 = __fadd_rn(r2, __shfl_xor(r2, 1));
        a2 = __fadd_rn(a2, __shfl_xor(a2, 2));
        a2 = __fadd_rn(a2, __shfl_xor(a2, 4));
        float* lsum = sh;
        #pragma unroll
        for (int c = 0; c < 3; ++c) {
            float rc = (c == 0) ? a0 : ((c == 1) ? a1 : a2);
            __syncthreads();
            if (j == 0) lsum[t >> 3] = rc;
            __syncthreads();
            for (int m = 16; m >= 1; m >>= 1) {
                float v = 0.0f;
                if (t < m) v = __fadd_rn(lsum[2 * t], lsum[2 * t + 1]);
                __syncthreads();
                if (t < m) lsum[t] = v;
                __syncthreads();
            }
            if (t == 0) wsf[16 + ((size_t)(b * 3 + c) * 32 + s) * 8 + blk] = lsum[0];
        }
    }
}

// ---------------- L2: PW pass 2 (mean reduced in-block, bit-exact) ----------
__global__ __launch_bounds__(256) void kpw2(const float* __restrict__ relc0,
                                            float* __restrict__ wsf) {
    __shared__ float msh[3];
    __shared__ float lsum[32];
    int bx = blockIdx.x;
    int s = bx >> 3, blk = bx & 7;
    int b = blockIdx.y;
    const float* relc = relc0 + (size_t)b * 3 * MTOT;
    int t = threadIdx.x;
    if (t < 3) msh[t] = reduce256(wsf + 16 + (size_t)(b * 3 + t) * 256) / 800000.0f;
    __syncthreads();
    float m0 = msh[0], m1 = msh[1], m2 = msh[2];
    int l = blk * 32 + (t >> 3);
    int j = t & 7;
    int off = 0, n = 25000;
    #pragma unroll
    for (int d = 7; d >= 0; --d) {
        int n2 = (n >> 1); n2 -= (n2 & 7);
        if ((l >> d) & 1) { off += n2; n -= n2; } else { n = n2; }
    }
    int base = s * 25000 + off;
    float r0 = 0.0f, r1 = 0.0f, r2 = 0.0f;
    for (int i = j; i < n; i += 8) {
        int f = base + i;
        float d0 = __fsub_rn(relc[f],            m0);
        float d1 = __fsub_rn(relc[MTOT + f],     m1);
        float d2 = __fsub_rn(relc[2 * MTOT + f], m2);
        r0 = __fadd_rn(r0, __fmul_rn(d0, d0));
        r1 = __fadd_rn(r1, __fmul_rn(d1, d1));
        r2 = __fadd_rn(r2, __fmul_rn(d2, d2));
    }
    float a0 = __fadd_rn(r0, __shfl_xor(r0, 1));
    a0 = __fadd_rn(a0, __shfl_xor(a0, 2));
    a0 = __fadd_rn(a0, __shfl_xor(a0, 4));
    float a1 = __fadd_rn(r1, __shfl_xor(r1, 1));
    a1 = __fadd_rn(a1, __shfl_xor(a1, 2));
    a1 = __fadd_rn(a1, __shfl_xor(a1, 4));
    float a2 = __fadd_rn(r2, __shfl_xor(r2, 1));
    a2 = __fadd_rn(a2, __shfl_xor(a2, 2));
    a2 = __fadd_rn(a2, __shfl_xor(a2, 4));
    #pragma unroll
    for (int c = 0; c < 3; ++c) {
        float rc = (c == 0) ? a0 : ((c == 1) ? a1 : a2);
        __syncthreads();
        if (j == 0) lsum[t >> 3] = rc;
        __syncthreads();
        for (int m = 16; m >= 1; m >>= 1) {
            float v = 0.0f;
            if (t < m) v = __fadd_rn(lsum[2 * t], lsum[2 * t + 1]);
            __syncthreads();
            if (t < m) lsum[t] = v;
            __syncthreads();
        }
        if (t == 0) wsf[2048 + ((size_t)(b * 3 + c) * 32 + s) * 8 + blk] = lsum[0];
    }
}

// ---------------- L3: kmain — p-per-half-wave uint gathers, lane-local ------
__global__ __launch_bounds__(256, 4) void kmain(const float* __restrict__ xyz,
                                                const int* __restrict__ idx,
                                                const float* __restrict__ cb,
                                                const float* __restrict__ dw,
                                                const unsigned short* __restrict__ g,
                                                const float* __restrict__ wsf,
                                                float* __restrict__ out) {
    __shared__ unsigned int  dwp[NCELL * 32];    // [cell][u] packed bf16 pair, 16000B
    __shared__ int           idxlds[64 * KNN];   // 4096B
    __shared__ unsigned char celllds[64 * KNN];  // 1024B
    __shared__ float         ctr[3][64];         // 768B
    __shared__ float         den[3];
    __shared__ float         res[128 * 33];      // 16896B  (total ~38.8KB)
    int b = blockIdx.y;
    int n0 = blockIdx.x * 64;
    int t = threadIdx.x;
    int nrem = NPTS - n0; if (nrem > 64) nrem = 64;

    if (t < 3) {   // denom, bit-exact kfin pass-2 replica
        float S = reduce256(wsf + 2048 + (size_t)(b * 3 + t) * 256);
        den[t] = __fmul_rn(4.0f, sqrtf(S / 799999.0f));
    }
    for (int i = t; i < NCELL * 32; i += 256) {
        int cell = i >> 5, u = i & 31;
        __hip_bfloat16 h0 = __float2bfloat16(dw[(2 * u)     * NCELL + cell]);
        __hip_bfloat16 h1 = __float2bfloat16(dw[(2 * u + 1) * NCELL + cell]);
        dwp[i] = (unsigned int)(*(unsigned short*)&h0) |
                 ((unsigned int)(*(unsigned short*)&h1) << 16);
    }
    const float* xb = xyz + (size_t)b * 3 * NPTS;
    if (t < 192) {
        int c = t >> 6, jx = t & 63;
        if (jx < nrem) ctr[c][jx] = xb[c * NPTS + n0 + jx];
    }
    const int* ib = idx + ((size_t)b * NPTS + n0) * KNN;
    __syncthreads();

    float dn0 = den[0], dn1 = den[1], dn2 = den[2];
    for (int i = t; i < nrem * KNN; i += 256) {
        int p = i >> 4;
        int jx = ib[i];
        idxlds[i] = jx;
        float sx = __fsub_rn(xb[jx],            ctr[0][p]) / dn0;
        float sy = __fsub_rn(xb[NPTS + jx],     ctr[1][p]) / dn1;
        float sz = __fsub_rn(xb[2 * NPTS + jx], ctr[2][p]) / dn2;
        celllds[i] = (unsigned char)((to_cell32(sz) * 5 + to_cell32(sy)) * 5 + to_cell32(sx));
    }
    __syncthreads();

    int w = t >> 6, h = (t >> 5) & 1, u = t & 31;
    int o0 = 2 * u, o1 = 2 * u + 1;
    float cb0 = cb[o0], cb1 = cb[o1];
    const unsigned short* gbp = g + (size_t)b * NPTS * C2;
    float* ob = out + (size_t)b * 128 * NPTS;

    for (int chunk = 0; chunk < 2; ++chunk) {
        int pbase = chunk * 32;
        #pragma unroll 1
        for (int i = 0; i < 4; ++i) {
            int p = pbase + i * 8 + w * 2 + h;
            if (p < nrem) {
                unsigned int gnv = *(const unsigned int*)(gbp + (size_t)(n0 + p) * C2 + o0);
                float gn0 = bflo(gnv), gn1 = bfhi(gnv);
                int cell0 = celllds[p * KNN];
                unsigned int dp0 = dwp[cell0 * 32 + u];
                float k00 = bflo(dp0), k01 = bfhi(dp0);
                float ws0 = 0, ws1 = 0, gs0 = 0, gs1 = 0, sk0 = 0, sk1 = 0;
                #pragma unroll
                for (int k = 1; k < 16; ++k) {
                    int jj   = idxlds[p * KNN + k];
                    int cell = celllds[p * KNN + k];
                    unsigned int gv = *(const unsigned int*)(gbp + (size_t)jj * C2 + o0);
                    unsigned int dp = dwp[cell * 32 + u];
                    float g0 = bflo(gv), g1 = bfhi(gv);
                    float kw0 = bflo(dp), kw1 = bfhi(dp);
                    ws0 = fmaf(kw0, g0, ws0); ws1 = fmaf(kw1, g1, ws1);
                    gs0 += g0; gs1 += g1; sk0 += kw0; sk1 += kw1;
                }
                int pl = p & 31;
                res[o0 * 33 + pl]        = cb0 * (k00 + sk0) + gn0 * (k00 - sk0) + ws0;
                res[o1 * 33 + pl]        = cb1 * (k01 + sk1) + gn1 * (k01 - sk1) + ws1;
                res[(64 + o0) * 33 + pl] = cb0 + 0.0625f * (gs0 - 14.0f * gn0);
                res[(64 + o1) * 33 + pl] = cb1 + 0.0625f * (gs1 - 14.0f * gn1);
            }
        }
        __syncthreads();
        int rl = t >> 5;            // 0..7: wave covers 2 rows/iter
        int jn = t & 31;
        int ncol = nrem - pbase; if (ncol > 32) ncol = 32;
        if (jn < ncol) {
            for (int r = rl; r < 128; r += 8)
                ob[(size_t)r * NPTS + n0 + pbase + jn] = res[r * 33 + jn];
        }
        __syncthreads();
    }
}

extern "C" void kernel_launch(void* const* d_in, const int* in_sizes, int n_in,
                              void* d_out, int out_size, void* d_ws, size_t ws_size,
                              hipStream_t stream) {
    const float* xyz   = (const float*)d_in[0];
    const float* fea   = (const float*)d_in[1];
    const int*   knn   = (const int*)d_in[2];
    const float* convw = (const float*)d_in[3];
    const float* convb = (const float*)d_in[4];
    const float* convdw= (const float*)d_in[5];
    float* out = (float*)d_out;
    float* wsf = (float*)d_ws;
    unsigned short* g = (unsigned short*)(wsf + 4096);
    float* relc = out;               // 4.8M floats scratch, fully overwritten by kmain

    int ntiles = (NPTS + 63) / 64;   // 782
    kfuse1<<<1564 + 512, 256, 0, stream>>>(xyz, knn, fea, convw, g, relc, wsf);
    kpw2  <<<dim3(256, BATCH), 256, 0, stream>>>(relc, wsf);
    kmain <<<dim3(ntiles, BATCH), 256, 0, stream>>>(xyz, knn, convb, convdw, g, wsf, out);
}